// Round 7
// baseline (1717.544 us; speedup 1.0000x reference)
//
#include <hip/hip_runtime.h>
#include <math.h>

#define Bn 128
#define Tn 512
#define Dn 32
#define Hn 128
#define Gn 512   // 4*H
#define Ln 3
#define MI 16    // items per mfma_scan block

// LDS-only barrier: does NOT drain vmcnt.
#define BAR_LDS() asm volatile("s_waitcnt lgkmcnt(0)\n\ts_barrier" ::: "memory")

typedef _Float16 h2 __attribute__((ext_vector_type(2)));
typedef _Float16 half4 __attribute__((ext_vector_type(4)));
typedef _Float16 half8 __attribute__((ext_vector_type(8)));   // MFMA A/B frag
typedef float f32x4 __attribute__((ext_vector_type(4)));      // MFMA acc

__device__ __forceinline__ float dot2(h2 a, h2 b, float c) {
    return __builtin_amdgcn_fdot2(a, b, c, false);
}
__device__ __forceinline__ h2 pkh(float a, float b) {
    h2 r; r.x = (_Float16)a; r.y = (_Float16)b; return r;
}
__device__ __forceinline__ float sigm(float x) {
    return __builtin_amdgcn_rcpf(1.f + __expf(-x));
}
__device__ __forceinline__ float tanh_fast(float x) {
    return 1.f - 2.f * __builtin_amdgcn_rcpf(1.f + __expf(2.f * x));
}

// ---------------------------------------------------------------------------
// fp32 -> fp16 convert (n multiple of 4)
// ---------------------------------------------------------------------------
__global__ __launch_bounds__(256) void cvt_f2h(
    const float* __restrict__ in, _Float16* __restrict__ out, int n)
{
    int base = (blockIdx.x * 256 + threadIdx.x) * 4;
    if (base < n) {
        float4 v = *(const float4*)(in + base);
        *(h2*)(out + base)     = pkh(v.x, v.y);
        *(h2*)(out + base + 2) = pkh(v.z, v.w);
    }
}

// ---------------------------------------------------------------------------
// MFMA GEMM: pre[M,512] = Ah[M,K] * Wh[512,K]^T + (b_ih + b_hh), fp16 output.
// Row m = b*512 + t (tch=512). Verified fragment layouts:
// A[m=lane&15][k=(lane>>4)*8+j], C/D row=(lane>>4)*4+reg, col=lane&15.
// ---------------------------------------------------------------------------
__global__ __launch_bounds__(256) void gemm_pre_mfma(
    const _Float16* __restrict__ A, int K, int rowStrideB, int t0, int tlog,
    const _Float16* __restrict__ W,
    const float* __restrict__ bi, const float* __restrict__ bh,
    _Float16* __restrict__ C)
{
    __shared__ h2 As2[64][20];
    __shared__ h2 Bs2[64][20];
    const int tid  = threadIdx.x;
    const int row0 = blockIdx.x * 64;
    const int col0 = blockIdx.y * 64;
    const int w    = tid >> 6;
    const int lane = tid & 63;
    const int qm   = (w >> 1) * 32;
    const int qn   = (w & 1) * 32;
    const int fm   = lane & 15;
    const int fq   = lane >> 4;
    const int tmask = (1 << tlog) - 1;
    const int lrow = tid >> 2;
    const int lk   = (tid & 3) * 8;

    f32x4 acc00 = {0,0,0,0}, acc01 = {0,0,0,0};
    f32x4 acc10 = {0,0,0,0}, acc11 = {0,0,0,0};

    for (int k0 = 0; k0 < K; k0 += 32) {
        {
            int rg = row0 + lrow;
            int b_idx = rg >> tlog, tt = rg & tmask;
            const _Float16* ap = A + (size_t)b_idx * rowStrideB +
                                 (size_t)(t0 + tt) * K + (k0 + lk);
            *(float4*)&As2[lrow][(tid & 3) * 4] = *(const float4*)ap;
            const _Float16* wp = W + (size_t)(col0 + lrow) * K + (k0 + lk);
            *(float4*)&Bs2[lrow][(tid & 3) * 4] = *(const float4*)wp;
        }
        __syncthreads();
        half8 a0 = *(const half8*)&As2[qm + fm][fq * 4];
        half8 a1 = *(const half8*)&As2[qm + 16 + fm][fq * 4];
        half8 b0 = *(const half8*)&Bs2[qn + fm][fq * 4];
        half8 b1 = *(const half8*)&Bs2[qn + 16 + fm][fq * 4];
        acc00 = __builtin_amdgcn_mfma_f32_16x16x32_f16(a0, b0, acc00, 0, 0, 0);
        acc01 = __builtin_amdgcn_mfma_f32_16x16x32_f16(a0, b1, acc01, 0, 0, 0);
        acc10 = __builtin_amdgcn_mfma_f32_16x16x32_f16(a1, b0, acc10, 0, 0, 0);
        acc11 = __builtin_amdgcn_mfma_f32_16x16x32_f16(a1, b1, acc11, 0, 0, 0);
        __syncthreads();
    }

    const int g0 = col0 + qn + fm;
    const int g1 = g0 + 16;
    const float bb0 = bi[g0] + bh[g0];
    const float bb1 = bi[g1] + bh[g1];
    const int m0 = row0 + qm + fq * 4;
    #pragma unroll
    for (int r = 0; r < 4; r++) {
        C[(size_t)(m0 + r) * Gn + g0]      = (_Float16)(acc00[r] + bb0);
        C[(size_t)(m0 + r) * Gn + g1]      = (_Float16)(acc01[r] + bb1);
        C[(size_t)(m0 + 16 + r) * Gn + g0] = (_Float16)(acc10[r] + bb0);
        C[(size_t)(m0 + 16 + r) * Gn + g1] = (_Float16)(acc11[r] + bb1);
    }
}

// ---------------------------------------------------------------------------
// mfma_scan: batched-MFMA LSTM recurrence. 8 blocks x 512 thr; block owns
// MI=16 items. Per tick: C[512 gates][16 items] = W_hh * h via 16x16x32 MFMA.
// Wave w owns all 4 gate-rows of units w*16..w*16+15 (A-frags pinned: 64
// VGPR). B = h[item][unit] in LDS (272 B row stride, conflict-free b128),
// double-buffered, ONE barrier/tick. C mapping puts i,f,g,o of unit
// (w*16+fq*4+r), item fm in one lane -> c-state in 4 regs, acts in-lane,
// zero reductions. acc seeded from pre (bias folded by gemm).
// ---------------------------------------------------------------------------
__global__ __launch_bounds__(512)
void mfma_scan(
    const _Float16* __restrict__ pre,    // [B*Tn, 512] fp16
    const _Float16* __restrict__ whh16,  // [512, 128] fp16 (this layer)
    _Float16* __restrict__ hs16)         // [B, Tn, 128] fp16 out
{
    const int tid  = threadIdx.x;
    const int w    = tid >> 6;          // wave: units w*16..+15
    const int lane = tid & 63;
    const int fm   = lane & 15;         // item within block / A-frag row
    const int fq   = lane >> 4;         // k-quarter within frag
    const int item = blockIdx.x * MI + fm;

    __shared__ __align__(16) _Float16 hL[2][MI][136];  // 272 B row stride

    // A-frags: [gate][k-step], each 8 fp16. Row = W_hh[g*128 + w*16 + fm].
    half8 af[4][4];
    #pragma unroll
    for (int g = 0; g < 4; g++)
        #pragma unroll
        for (int ks = 0; ks < 4; ks++)
            af[g][ks] = *(const half8*)(whh16 +
                (size_t)(g * Hn + w * 16 + fm) * Hn + ks * 32 + fq * 8);

    for (int i = tid; i < 2 * MI * 136; i += 512)
        ((_Float16*)hL)[i] = (_Float16)0;

    const _Float16* pp = pre + (size_t)item * Tn * Gn + w * 16 + fq * 4;
    _Float16* hw = hs16 + (size_t)item * Tn * Hn + w * 16 + fq * 4;

    // prefetch pre rows t=0,1 (4 gates x 4 units each)
    half4 p0[4], p1[4];
    #pragma unroll
    for (int g = 0; g < 4; g++) {
        p0[g] = *(const half4*)(pp + g * Hn);
        p1[g] = *(const half4*)(pp + Gn + g * Hn);
    }
    const _Float16* pld = pp + 2 * (size_t)Gn;

    float cst[4] = {0.f, 0.f, 0.f, 0.f};
    __syncthreads();

    for (int t = 0; t < Tn; t++) {
        // B-frags: h of my item, k-runs per k-step
        const _Float16* hr = &hL[t & 1][fm][fq * 8];
        half8 bf0 = *(const half8*)(hr);
        half8 bf1 = *(const half8*)(hr + 32);
        half8 bf2 = *(const half8*)(hr + 64);
        half8 bf3 = *(const half8*)(hr + 96);

        f32x4 acc[4];
        #pragma unroll
        for (int g = 0; g < 4; g++) {
            acc[g][0] = (float)p0[g][0];
            acc[g][1] = (float)p0[g][1];
            acc[g][2] = (float)p0[g][2];
            acc[g][3] = (float)p0[g][3];
        }

        // rotate prefetch; issue loads for t+2
        #pragma unroll
        for (int g = 0; g < 4; g++) p0[g] = p1[g];
        if (t + 2 < Tn) {
            #pragma unroll
            for (int g = 0; g < 4; g++)
                p1[g] = *(const half4*)(pld + g * Hn);
            pld += Gn;
        }

        #pragma unroll
        for (int g = 0; g < 4; g++) {
            acc[g] = __builtin_amdgcn_mfma_f32_16x16x32_f16(af[g][0], bf0, acc[g], 0, 0, 0);
            acc[g] = __builtin_amdgcn_mfma_f32_16x16x32_f16(af[g][1], bf1, acc[g], 0, 0, 0);
            acc[g] = __builtin_amdgcn_mfma_f32_16x16x32_f16(af[g][2], bf2, acc[g], 0, 0, 0);
            acc[g] = __builtin_amdgcn_mfma_f32_16x16x32_f16(af[g][3], bf3, acc[g], 0, 0, 0);
        }

        half4 hh;
        #pragma unroll
        for (int r = 0; r < 4; r++) {
            float iv = sigm(acc[0][r]);
            float fv = sigm(acc[1][r]);
            float gv = tanh_fast(acc[2][r]);
            float ov = sigm(acc[3][r]);
            cst[r] = fv * cst[r] + iv * gv;
            hh[r] = (_Float16)(ov * tanh_fast(cst[r]));
        }
        // next-tick h buffer + trajectory
        *(half4*)&hL[(t + 1) & 1][fm][w * 16 + fq * 4] = hh;
        *(half4*)hw = hh;
        hw += Hn;
        BAR_LDS();
    }
}

// ---------------------------------------------------------------------------
// Attention pooling + MLP head (reads fp16 hs). One block per batch item.
// ---------------------------------------------------------------------------
__global__ __launch_bounds__(256) void head_kernel(
    const _Float16* __restrict__ hs16,
    const float* __restrict__ w_attn, const float* __restrict__ b_attn,
    const float* __restrict__ w1, const float* __restrict__ b1,
    const float* __restrict__ w2, const float* __restrict__ b2,
    float* __restrict__ out)
{
    const int b = blockIdx.x;
    const int tid = threadIdx.x;
    __shared__ h2 wa2[Hn / 2];
    __shared__ __align__(16) float sc[Tn];
    __shared__ __align__(16) float red[256];
    __shared__ __align__(16) float ctx_sh[Hn];
    __shared__ __align__(16) float h1_sh[64];

    if (tid < Hn / 2) wa2[tid] = pkh(w_attn[2 * tid], w_attn[2 * tid + 1]);
    __syncthreads();

    const _Float16* hb = hs16 + (size_t)b * Tn * Hn;

    for (int t = tid; t < Tn; t += 256) {
        const h2* hp = (const h2*)(hb + (size_t)t * Hn);
        float s = 0.f;
        #pragma unroll
        for (int k = 0; k < 64; k++) s = dot2(hp[k], wa2[k], s);
        sc[t] = s + b_attn[0];
    }
    __syncthreads();

    float m = fmaxf(sc[tid], sc[tid + 256]);
    red[tid] = m; __syncthreads();
    for (int s_ = 128; s_ > 0; s_ >>= 1) {
        if (tid < s_) red[tid] = fmaxf(red[tid], red[tid + s_]);
        __syncthreads();
    }
    float mx = red[0];
    __syncthreads();
    float e0 = __expf(sc[tid] - mx), e1 = __expf(sc[tid + 256] - mx);
    sc[tid] = e0; sc[tid + 256] = e1;
    red[tid] = e0 + e1; __syncthreads();
    for (int s_ = 128; s_ > 0; s_ >>= 1) {
        if (tid < s_) red[tid] += red[tid + s_];
        __syncthreads();
    }
    float inv = 1.f / red[0];
    __syncthreads();

    {
        int jj = tid & 127, half = tid >> 7;
        float a = 0.f;
        for (int t = half * 256; t < half * 256 + 256; t++)
            a += sc[t] * (float)hb[(size_t)t * Hn + jj];
        red[tid] = a;
        __syncthreads();
        if (tid < Hn) ctx_sh[tid] = (red[tid] + red[tid + Hn]) * inv;
        __syncthreads();
    }

    if (tid < 64) {
        const float4* wvv = (const float4*)(w1 + (size_t)tid * Hn);
        const float4* cv = (const float4*)ctx_sh;
        float s = 0.f;
        #pragma unroll
        for (int k = 0; k < 32; k++) {
            float4 a = wvv[k], c = cv[k];
            s += a.x * c.x + a.y * c.y + a.z * c.z + a.w * c.w;
        }
        h1_sh[tid] = fmaxf(s + b1[tid], 0.f);
    }
    __syncthreads();

    if (tid < 4) {
        float s = 0.f;
        const float* wvv = w2 + tid * 64;
        #pragma unroll
        for (int k = 0; k < 64; k++) s += wvv[k] * h1_sh[k];
        out[b * 4 + tid] = s + b2[tid];
    }
}

// ---------------------------------------------------------------------------
extern "C" void kernel_launch(void* const* d_in, const int* in_sizes, int n_in,
                              void* d_out, int out_size, void* d_ws, size_t ws_size,
                              hipStream_t stream)
{
    const float* x        = (const float*)d_in[0];
    const float* w_ih0    = (const float*)d_in[1];
    const float* w_ih_rest= (const float*)d_in[2];
    const float* w_hh     = (const float*)d_in[3];
    const float* b_ih     = (const float*)d_in[4];
    const float* b_hh     = (const float*)d_in[5];
    const float* w_attn   = (const float*)d_in[6];
    const float* b_attn   = (const float*)d_in[7];
    const float* w1       = (const float*)d_in[8];
    const float* b1       = (const float*)d_in[9];
    const float* w2       = (const float*)d_in[10];
    const float* b2       = (const float*)d_in[11];
    float* out = (float*)d_out;

    const size_t nX   = (size_t)Bn * Tn * Dn;       // 2,097,152
    const size_t nHS  = (size_t)Bn * Tn * Hn;       // 8,388,608
    const size_t nW0  = (size_t)Gn * Dn;            // 16,384
    const size_t nWR  = (size_t)(Ln - 1) * Gn * Hn; // 131,072
    const size_t nWH  = (size_t)Ln * Gn * Hn;       // 196,608
    const size_t nPRE = (size_t)Bn * Tn * Gn;       // 33,554,432 (fp16)

    _Float16* preh  = (_Float16*)d_ws;
    _Float16* xh    = preh + nPRE;
    _Float16* hs0   = xh + nX;
    _Float16* hs1   = hs0 + nHS;
    _Float16* hs2   = hs1 + nHS;
    _Float16* w0h   = hs2 + nHS;
    _Float16* wrh   = w0h + nW0;
    _Float16* whh16 = wrh + nWR;
    // total ~119 MB fp16

    cvt_f2h<<<(int)((nX / 4 + 255) / 256), 256, 0, stream>>>(x, xh, (int)nX);
    cvt_f2h<<<(int)((nW0 / 4 + 255) / 256), 256, 0, stream>>>(w_ih0, w0h, (int)nW0);
    cvt_f2h<<<(int)((nWR / 4 + 255) / 256), 256, 0, stream>>>(w_ih_rest, wrh, (int)nWR);
    cvt_f2h<<<(int)((nWH / 4 + 255) / 256), 256, 0, stream>>>(w_hh, whh16, (int)nWH);

    for (int l = 0; l < Ln; l++) {
        const _Float16* A = (l == 0) ? xh : (l == 1 ? hs0 : hs1);
        int K = (l == 0) ? Dn : Hn;
        const _Float16* W = (l == 0) ? w0h : (wrh + (size_t)(l - 1) * Gn * Hn);
        _Float16* hsOut = (l == 0) ? hs0 : (l == 1 ? hs1 : hs2);

        gemm_pre_mfma<<<dim3(Bn * Tn / 64, 8), 256, 0, stream>>>(
            A, K, Tn * K, 0, 9, W, b_ih + l * Gn, b_hh + l * Gn, preh);
        mfma_scan<<<Bn / MI, 512, 0, stream>>>(
            preh, whh16 + (size_t)l * Gn * Hn, hsOut);
    }

    head_kernel<<<Bn, 256, 0, stream>>>(hs2, w_attn, b_attn, w1, b1, w2, b2, out);
}